// Round 1
// baseline (1121.394 us; speedup 1.0000x reference)
//
#include <hip/hip_runtime.h>
#include <math.h>

#define NPTS 16384
#define KG 20
#define KN 10
#define NCHUNK 8
#define CHUNKSZ (NPTS / NCHUNK)
#define EPSF 1e-8f

// ---------------------------------------------------------------- pos concat
__global__ __launch_bounds__(256) void pos4_kernel(const float* __restrict__ pts,
                                                   const float* __restrict__ als,
                                                   float4* __restrict__ pos4) {
  int n = blockIdx.x * 256 + threadIdx.x;
  if (n >= NPTS) return;
  const float* src = (n < 8192) ? (pts + (size_t)n * 3) : (als + (size_t)(n - 8192) * 3);
  pos4[n] = make_float4(src[0], src[1], src[2], 0.f);
}

// ---------------------------------------------------------------- knn (chunked)
__global__ __launch_bounds__(256) void knn_chunk_kernel(const float4* __restrict__ pos4,
                                                        float* __restrict__ cdist,
                                                        int* __restrict__ cidx) {
  __shared__ float4 tile[512];
  int q = blockIdx.x * 256 + threadIdx.x;
  int chunk = blockIdx.y;
  float4 p = pos4[q];
  float dist[KG];
  int idx[KG];
#pragma unroll
  for (int i = 0; i < KG; ++i) { dist[i] = 3.4e38f; idx[i] = 0; }
  int cbase = chunk * CHUNKSZ;
  for (int t0 = 0; t0 < CHUNKSZ; t0 += 512) {
    __syncthreads();
    for (int j = threadIdx.x; j < 512; j += 256) tile[j] = pos4[cbase + t0 + j];
    __syncthreads();
    for (int j = 0; j < 512; ++j) {
      float4 c = tile[j];
      float dx = c.x - p.x, dy = c.y - p.y, dz = c.z - p.z;
      float d2 = dx * dx + dy * dy + dz * dz;
      if (d2 < dist[KG - 1]) {
        dist[KG - 1] = d2; idx[KG - 1] = cbase + t0 + j;
#pragma unroll
        for (int s = KG - 1; s > 0; --s) {
          if (dist[s] < dist[s - 1]) {
            float td = dist[s]; dist[s] = dist[s - 1]; dist[s - 1] = td;
            int ti = idx[s]; idx[s] = idx[s - 1]; idx[s - 1] = ti;
          }
        }
      }
    }
  }
  size_t base = ((size_t)q * NCHUNK + chunk) * KG;
#pragma unroll
  for (int i = 0; i < KG; ++i) { cdist[base + i] = dist[i]; cidx[base + i] = idx[i]; }
}

__global__ __launch_bounds__(256) void knn_merge_kernel(const float* __restrict__ cdist,
                                                        const int* __restrict__ cidx,
                                                        int* __restrict__ nbr) {
  int q = blockIdx.x * 256 + threadIdx.x;
  if (q >= NPTS) return;
  float dist[KG];
  int idx[KG];
#pragma unroll
  for (int i = 0; i < KG; ++i) { dist[i] = 3.4e38f; idx[i] = 0; }
  size_t base = (size_t)q * NCHUNK * KG;
  for (int j = 0; j < NCHUNK * KG; ++j) {
    float d = cdist[base + j];
    if (d < dist[KG - 1]) {
      int id = cidx[base + j];
      dist[KG - 1] = d; idx[KG - 1] = id;
#pragma unroll
      for (int s = KG - 1; s > 0; --s) {
        if (dist[s] < dist[s - 1]) {
          float td = dist[s]; dist[s] = dist[s - 1]; dist[s - 1] = td;
          int ti = idx[s]; idx[s] = idx[s - 1]; idx[s - 1] = ti;
        }
      }
    }
  }
#pragma unroll
  for (int i = 0; i < KG; ++i) nbr[(size_t)q * KG + i] = idx[i];
}

// ---------------------------------------------------------------- basis (normal + tangent frame)
__global__ __launch_bounds__(256) void basis_kernel(const float4* __restrict__ pos4,
                                                    const int* __restrict__ nbr,
                                                    float4* __restrict__ xb4,
                                                    float4* __restrict__ yb4) {
  int n = blockIdx.x * 256 + threadIdx.x;
  if (n >= NPTS) return;
  float4 p = pos4[n];
  double c00 = 0, c01 = 0, c02 = 0, c11 = 0, c12 = 0, c22 = 0;
  for (int k = 0; k < KN; ++k) {
    int m = nbr[(size_t)n * KG + k];
    float4 pm = pos4[m];
    double dx = (double)pm.x - p.x, dy = (double)pm.y - p.y, dz = (double)pm.z - p.z;
    c00 += dx * dx; c01 += dx * dy; c02 += dx * dz;
    c11 += dy * dy; c12 += dy * dz; c22 += dz * dz;
  }
  double nx = 0, ny = 0, nz = 1;
  double p1 = c01 * c01 + c02 * c02 + c12 * c12;
  double qm = (c00 + c11 + c22) / 3.0;
  double g0 = c00 - qm, g1 = c11 - qm, g2 = c22 - qm;
  double p2 = g0 * g0 + g1 * g1 + g2 * g2 + 2.0 * p1;
  if (p2 > 1e-26) {
    double pp = sqrt(p2 / 6.0);
    double inv = 1.0 / pp;
    double b00 = g0 * inv, b11 = g1 * inv, b22 = g2 * inv;
    double b01 = c01 * inv, b02 = c02 * inv, b12 = c12 * inv;
    double detB = b00 * (b11 * b22 - b12 * b12) - b01 * (b01 * b22 - b12 * b02) +
                  b02 * (b01 * b12 - b11 * b02);
    double r = 0.5 * detB;
    r = fmin(1.0, fmax(-1.0, r));
    double phi = acos(r) / 3.0;
    double e1 = qm + 2.0 * pp * cos(phi);
    double e3 = qm + 2.0 * pp * cos(phi + 2.0943951023931953);
    double e2 = 3.0 * qm - e1 - e3;
    // M = (A-e1 I)(A-e2 I): columns span the e3 (smallest) eigenspace
    double a00 = c00 - e1, a11 = c11 - e1, a22 = c22 - e1;
    double f00 = c00 - e2, f11 = c11 - e2, f22 = c22 - e2;
    double u0 = a00 * f00 + c01 * c01 + c02 * c02;
    double u1 = c01 * f00 + a11 * c01 + c12 * c02;
    double u2 = c02 * f00 + c12 * c01 + a22 * c02;
    double v0 = a00 * c01 + c01 * f11 + c02 * c12;
    double v1 = c01 * c01 + a11 * f11 + c12 * c12;
    double v2 = c02 * c01 + c12 * f11 + a22 * c12;
    double w0 = a00 * c02 + c01 * c12 + c02 * f22;
    double w1 = c01 * c02 + a11 * c12 + c12 * f22;
    double w2 = c02 * c02 + c12 * c12 + a22 * f22;
    double nu = u0 * u0 + u1 * u1 + u2 * u2;
    double nv = v0 * v0 + v1 * v1 + v2 * v2;
    double nw = w0 * w0 + w1 * w1 + w2 * w2;
    double bx = u0, by = u1, bz = u2, bn = nu;
    if (nv > bn) { bx = v0; by = v1; bz = v2; bn = nv; }
    if (nw > bn) { bx = w0; by = w1; bz = w2; bn = nw; }
    if (bn > 1e-40) {
      double s = 1.0 / sqrt(bn);
      nx = bx * s; ny = by * s; nz = bz * s;
    }
  }
  double dotp = nx * p.x + ny * p.y + nz * p.z;
  if (dotp < 0.0) { nx = -nx; ny = -ny; nz = -nz; }
  // tangent frame: xb = normalize(cross(n, e_least)), yb = cross(n, xb)
  double ax = fabs(nx), ay = fabs(ny), az = fabs(nz);
  double ex = 0, ey = 0, ez = 0;
  if (ax <= ay && ax <= az) ex = 1;
  else if (ay <= az) ey = 1;
  else ez = 1;
  double tx = ny * ez - nz * ey, ty = nz * ex - nx * ez, tz = nx * ey - ny * ex;
  double tn = 1.0 / sqrt(tx * tx + ty * ty + tz * tz);
  tx *= tn; ty *= tn; tz *= tn;
  double ux = ny * tz - nz * ty, uy = nz * tx - nx * tz, uz = nx * ty - ny * tx;
  xb4[n] = make_float4((float)tx, (float)ty, (float)tz, 0.f);
  yb4[n] = make_float4((float)ux, (float)uy, (float)uz, 0.f);
}

// ---------------------------------------------------------------- Gx/Gy/R + v0 = grad(pos)
__global__ __launch_bounds__(256) void graddiv_kernel(const float4* __restrict__ pos4,
                                                      const int* __restrict__ nbr,
                                                      const float4* __restrict__ xb4,
                                                      const float4* __restrict__ yb4,
                                                      float* __restrict__ Gx,
                                                      float* __restrict__ Gy,
                                                      float* __restrict__ R,
                                                      float* __restrict__ v0) {
  int n = blockIdx.x * 256 + threadIdx.x;
  if (n >= NPTS) return;
  float4 p = pos4[n], xb = xb4[n], yb = yb4[n];
  float u[KG], vv[KG], w[KG];
  int mm[KG];
  float hsum = 0.f;
#pragma unroll
  for (int k = 0; k < KG; ++k) {
    int m = nbr[(size_t)n * KG + k];
    mm[k] = m;
    float4 pm = pos4[m];
    float rx = pm.x - p.x, ry = pm.y - p.y, rz = pm.z - p.z;
    u[k] = rx * xb.x + ry * xb.y + rz * xb.z;
    vv[k] = rx * yb.x + ry * yb.y + rz * yb.z;
    float dd = sqrtf(rx * rx + ry * ry + rz * rz + EPSF);
    w[k] = dd; hsum += dd;
  }
  float h = hsum * (1.f / KG);
  float invden = 1.f / (h * h + EPSF);
  double A00 = 0, A01 = 0, A02 = 0, A11 = 0, A12 = 0, A22 = 0;
#pragma unroll
  for (int k = 0; k < KG; ++k) {
    float wk = expf(-(w[k] * w[k]) * invden);
    w[k] = wk;
    A00 += wk; A01 += (double)wk * u[k]; A02 += (double)wk * vv[k];
    A11 += (double)wk * u[k] * u[k]; A12 += (double)wk * u[k] * vv[k];
    A22 += (double)wk * vv[k] * vv[k];
  }
  A00 += 0.001; A11 += 0.001; A22 += 0.001;
  double det = A00 * (A11 * A22 - A12 * A12) - A01 * (A01 * A22 - A12 * A02) +
               A02 * (A01 * A12 - A11 * A02);
  double idet = 1.0 / det;
  float i10 = (float)((A02 * A12 - A01 * A22) * idet);
  float i11 = (float)((A00 * A22 - A02 * A02) * idet);
  float i12 = (float)((A01 * A02 - A00 * A12) * idet);
  float i20 = (float)((A01 * A12 - A02 * A11) * idet);
  float i21 = i12;
  float i22 = (float)((A00 * A11 - A01 * A01) * idet);
  float a0x = 0, a0y = 0, a0z = 0, a1x = 0, a1y = 0, a1z = 0;
#pragma unroll
  for (int k = 0; k < KG; ++k) {
    float gx = w[k] * (i10 + i11 * u[k] + i12 * vv[k]);
    float gy = w[k] * (i20 + i21 * u[k] + i22 * vv[k]);
    Gx[(size_t)n * KG + k] = gx;
    Gy[(size_t)n * KG + k] = gy;
    int m = mm[k];
    float4 pm = pos4[m];
    a0x += gx * pm.x; a0y += gx * pm.y; a0z += gx * pm.z;
    a1x += gy * pm.x; a1y += gy * pm.y; a1z += gy * pm.z;
    float4 xm = xb4[m], ym = yb4[m];
    size_t rb = ((size_t)n * KG + k) * 4;
    R[rb + 0] = xb.x * xm.x + xb.y * xm.y + xb.z * xm.z;
    R[rb + 1] = xb.x * ym.x + xb.y * ym.y + xb.z * ym.z;
    R[rb + 2] = yb.x * xm.x + yb.y * xm.y + yb.z * xm.z;
    R[rb + 3] = yb.x * ym.x + yb.y * ym.y + yb.z * ym.z;
  }
  v0[((size_t)n * 2 + 0) * 3 + 0] = a0x;
  v0[((size_t)n * 2 + 0) * 3 + 1] = a0y;
  v0[((size_t)n * 2 + 0) * 3 + 2] = a0z;
  v0[((size_t)n * 2 + 1) * 3 + 0] = a1x;
  v0[((size_t)n * 2 + 1) * 3 + 1] = a1y;
  v0[((size_t)n * 2 + 1) * 3 + 2] = a1z;
}

// ---------------------------------------------------------------- feat = [xmax | div v | curl v]
template <int CENTRAL>
__global__ __launch_bounds__(256) void feat_kernel(const float* __restrict__ x, int ldx, int cin,
                                                   const float* __restrict__ v,
                                                   const int* __restrict__ nbr,
                                                   const float* __restrict__ Gx,
                                                   const float* __restrict__ Gy,
                                                   const float* __restrict__ R,
                                                   float* __restrict__ feat) {
  int gid = blockIdx.x * 256 + threadIdx.x;
  if (gid >= NPTS * cin) return;
  int n = gid / cin;
  int c = gid - n * cin;
  float xc = x[(size_t)n * ldx + c];
  float xmax = -3.4e38f, dv = 0.f, cv = 0.f;
  for (int k = 0; k < KG; ++k) {
    int m = nbr[(size_t)n * KG + k];
    float gx = Gx[(size_t)n * KG + k];
    float gy = Gy[(size_t)n * KG + k];
    float4 r = *reinterpret_cast<const float4*>(&R[((size_t)n * KG + k) * 4]);
    float xm = x[(size_t)m * ldx + c];
    xmax = fmaxf(xmax, CENTRAL ? (xm - xc) : xm);
    float va = v[((size_t)m * 2 + 0) * cin + c];
    float vb = v[((size_t)m * 2 + 1) * cin + c];
    dv += gx * (r.x * va + r.y * vb) + gy * (r.z * va + r.w * vb);
    cv += gx * (r.y * va - r.x * vb) + gy * (r.w * va - r.z * vb);
  }
  size_t fb = (size_t)n * (3 * cin);
  feat[fb + c] = xmax;
  feat[fb + cin + c] = dv;
  feat[fb + 2 * cin + c] = cv;
}

// ---------------------------------------------------------------- vin = [v | grad(x_out)]
__global__ __launch_bounds__(256) void vin_kernel(const float* __restrict__ v, int cin,
                                                  const float* __restrict__ xout, int cout,
                                                  const int* __restrict__ nbr,
                                                  const float* __restrict__ Gx,
                                                  const float* __restrict__ Gy,
                                                  float* __restrict__ vin, int total) {
  int gid = blockIdx.x * 256 + threadIdx.x;
  if (gid >= total) return;
  int K = cin + cout;
  int n = gid / K;
  int c = gid - n * K;
  if (c < cin) {
    vin[((size_t)n * 2 + 0) * K + c] = v[((size_t)n * 2 + 0) * cin + c];
    vin[((size_t)n * 2 + 1) * K + c] = v[((size_t)n * 2 + 1) * cin + c];
  } else {
    int cc = c - cin;
    float a0 = 0.f, a1 = 0.f;
    for (int k = 0; k < KG; ++k) {
      int m = nbr[(size_t)n * KG + k];
      float f = xout[(size_t)m * cout + cc];
      a0 += Gx[(size_t)n * KG + k] * f;
      a1 += Gy[(size_t)n * KG + k] * f;
    }
    vin[((size_t)n * 2 + 0) * K + c] = a0;
    vin[((size_t)n * 2 + 1) * K + c] = a1;
  }
}

// ---------------------------------------------------------------- vector norm gate
__global__ __launch_bounds__(256) void vnorm_kernel(float* __restrict__ v,
                                                    const float* __restrict__ bv, int cout) {
  int gid = blockIdx.x * 256 + threadIdx.x;
  if (gid >= NPTS * cout) return;
  int n = gid / cout;
  int c = gid - n * cout;
  size_t i0 = ((size_t)n * 2 + 0) * cout + c;
  size_t i1 = ((size_t)n * 2 + 1) * cout + c;
  float a = v[i0], b = v[i1];
  float nrm = sqrtf(a * a + b * b + EPSF);
  float s = fmaxf(nrm + bv[c], 0.f) / (nrm + EPSF);
  v[i0] = a * s;
  v[i1] = b * s;
}

// ---------------------------------------------------------------- f32 GEMM: C = relu(A@B + bias)
template <int RELU>
__global__ __launch_bounds__(256) void gemm_kernel(const float* __restrict__ A,
                                                   const float* __restrict__ B,
                                                   const float* __restrict__ bias,
                                                   float* __restrict__ C, int M, int K, int Ncol) {
  __shared__ float As[64][17];
  __shared__ float Bs[16][64];
  int tid = threadIdx.x;
  int tx = tid & 15, ty = tid >> 4;
  int rowBase = blockIdx.y * 64, colBase = blockIdx.x * 64;
  float acc[4][4] = {};
  int ar = tid >> 2, ak = (tid & 3) << 2;
  int kb = tid >> 4, cb = (tid & 15) << 2;
  for (int k0 = 0; k0 < K; k0 += 16) {
    __syncthreads();
#pragma unroll
    for (int i = 0; i < 4; ++i) {
      int kg = k0 + ak + i;
      As[ar][ak + i] = (kg < K) ? A[(size_t)(rowBase + ar) * K + kg] : 0.f;
    }
    {
      int kg = k0 + kb;
      float4 bvv = make_float4(0.f, 0.f, 0.f, 0.f);
      if (kg < K) bvv = *reinterpret_cast<const float4*>(&B[(size_t)kg * Ncol + colBase + cb]);
      Bs[kb][cb] = bvv.x; Bs[kb][cb + 1] = bvv.y; Bs[kb][cb + 2] = bvv.z; Bs[kb][cb + 3] = bvv.w;
    }
    __syncthreads();
#pragma unroll
    for (int kk = 0; kk < 16; ++kk) {
      float a0 = As[ty * 4 + 0][kk], a1 = As[ty * 4 + 1][kk];
      float a2 = As[ty * 4 + 2][kk], a3 = As[ty * 4 + 3][kk];
      float b0 = Bs[kk][tx * 4 + 0], b1 = Bs[kk][tx * 4 + 1];
      float b2 = Bs[kk][tx * 4 + 2], b3 = Bs[kk][tx * 4 + 3];
      acc[0][0] += a0 * b0; acc[0][1] += a0 * b1; acc[0][2] += a0 * b2; acc[0][3] += a0 * b3;
      acc[1][0] += a1 * b0; acc[1][1] += a1 * b1; acc[1][2] += a1 * b2; acc[1][3] += a1 * b3;
      acc[2][0] += a2 * b0; acc[2][1] += a2 * b1; acc[2][2] += a2 * b2; acc[2][3] += a2 * b3;
      acc[3][0] += a3 * b0; acc[3][1] += a3 * b1; acc[3][2] += a3 * b2; acc[3][3] += a3 * b3;
    }
  }
  float bj0 = 0.f, bj1 = 0.f, bj2 = 0.f, bj3 = 0.f;
  if (bias != nullptr) {
    bj0 = bias[colBase + tx * 4 + 0];
    bj1 = bias[colBase + tx * 4 + 1];
    bj2 = bias[colBase + tx * 4 + 2];
    bj3 = bias[colBase + tx * 4 + 3];
  }
#pragma unroll
  for (int i = 0; i < 4; ++i) {
    float o0 = acc[i][0] + bj0, o1 = acc[i][1] + bj1;
    float o2 = acc[i][2] + bj2, o3 = acc[i][3] + bj3;
    if (RELU) {
      o0 = fmaxf(o0, 0.f); o1 = fmaxf(o1, 0.f);
      o2 = fmaxf(o2, 0.f); o3 = fmaxf(o3, 0.f);
    }
    *reinterpret_cast<float4*>(&C[(size_t)(rowBase + ty * 4 + i) * Ncol + colBase + tx * 4]) =
        make_float4(o0, o1, o2, o3);
  }
}

// ---------------------------------------------------------------- launch
extern "C" void kernel_launch(void* const* d_in, const int* in_sizes, int n_in,
                              void* d_out, int out_size, void* d_ws, size_t ws_size,
                              hipStream_t stream) {
  const float* pts = (const float*)d_in[0];
  const float* als = (const float*)d_in[1];
  const float* Ws0 = (const float*)d_in[2];
  const float* bs0 = (const float*)d_in[3];
  const float* Wv0 = (const float*)d_in[4];
  const float* bv0 = (const float*)d_in[5];
  const float* Ws1 = (const float*)d_in[6];
  const float* bs1 = (const float*)d_in[7];
  const float* Wv1 = (const float*)d_in[8];
  const float* bv1 = (const float*)d_in[9];
  const float* Ws2 = (const float*)d_in[10];
  const float* bs2 = (const float*)d_in[11];

  char* ws = (char*)d_ws;
  float4* pos4 = (float4*)(ws + 0);            //  256 KB
  int* nbr = (int*)(ws + 262144);              // 1.31 MB
  float4* xb4 = (float4*)(ws + 1572864);       //  256 KB
  float4* yb4 = (float4*)(ws + 1835008);       //  256 KB
  float* Gx = (float*)(ws + 2097152);          // 1.31 MB
  float* Gy = (float*)(ws + 3407872);          // 1.31 MB
  float* R = (float*)(ws + 4718592);           // 5.24 MB
  float* v_a = (float*)(ws + 9961472);         // 16.78 MB (also knn idx scratch)
  float* v_b = (float*)(ws + 26738688);        // 16.78 MB
  float* sbuf = (float*)(ws + 43515904);       // 25.17 MB (feat/vin shared; also knn dist scratch)
  float* cdist = sbuf;
  int* cidx = (int*)v_a;

  float* out0 = (float*)d_out;           // (N,64)
  float* out1 = out0 + (size_t)NPTS * 64;  // (N,128)
  float* out2 = out1 + (size_t)NPTS * 128; // (N,256)

  pos4_kernel<<<64, 256, 0, stream>>>(pts, als, pos4);
  knn_chunk_kernel<<<dim3(64, NCHUNK), 256, 0, stream>>>(pos4, cdist, cidx);
  knn_merge_kernel<<<64, 256, 0, stream>>>(cdist, cidx, nbr);
  basis_kernel<<<64, 256, 0, stream>>>(pos4, nbr, xb4, yb4);
  graddiv_kernel<<<64, 256, 0, stream>>>(pos4, nbr, xb4, yb4, Gx, Gy, R, v_a);

  // ---- layer 0 (cin=3 -> cout=64, centralized)
  feat_kernel<1><<<(NPTS * 3 + 255) / 256, 256, 0, stream>>>((const float*)pos4, 4, 3, v_a, nbr,
                                                             Gx, Gy, R, sbuf);
  gemm_kernel<1><<<dim3(1, NPTS / 64), 256, 0, stream>>>(sbuf, Ws0, bs0, out0, NPTS, 9, 64);
  vin_kernel<<<(NPTS * 67 + 255) / 256, 256, 0, stream>>>(v_a, 3, out0, 64, nbr, Gx, Gy, sbuf,
                                                          NPTS * 67);
  gemm_kernel<0><<<dim3(1, 2 * NPTS / 64), 256, 0, stream>>>(sbuf, Wv0, nullptr, v_b, 2 * NPTS,
                                                             67, 64);
  vnorm_kernel<<<(NPTS * 64 + 255) / 256, 256, 0, stream>>>(v_b, bv0, 64);

  // ---- layer 1 (cin=64 -> cout=128)
  feat_kernel<0><<<(NPTS * 64 + 255) / 256, 256, 0, stream>>>(out0, 64, 64, v_b, nbr, Gx, Gy, R,
                                                              sbuf);
  gemm_kernel<1><<<dim3(2, NPTS / 64), 256, 0, stream>>>(sbuf, Ws1, bs1, out1, NPTS, 192, 128);
  vin_kernel<<<(NPTS * 192 + 255) / 256, 256, 0, stream>>>(v_b, 64, out1, 128, nbr, Gx, Gy, sbuf,
                                                           NPTS * 192);
  gemm_kernel<0><<<dim3(2, 2 * NPTS / 64), 256, 0, stream>>>(sbuf, Wv1, nullptr, v_a, 2 * NPTS,
                                                             192, 128);
  vnorm_kernel<<<(NPTS * 128 + 255) / 256, 256, 0, stream>>>(v_a, bv1, 128);

  // ---- layer 2 (cin=128 -> cout=256, no vector update)
  feat_kernel<0><<<(NPTS * 128 + 255) / 256, 256, 0, stream>>>(out1, 128, 128, v_a, nbr, Gx, Gy,
                                                               R, sbuf);
  gemm_kernel<1><<<dim3(4, NPTS / 64), 256, 0, stream>>>(sbuf, Ws2, bs2, out2, NPTS, 384, 256);
}